// Round 1
// baseline (266.987 us; speedup 1.0000x reference)
//
#include <hip/hip_runtime.h>
#include <stdint.h>

#define NN 8192
#define IN_DIM 32
#define HID_DIM 64
#define OUT_DIM 16

typedef __attribute__((ext_vector_type(8))) short short8;
typedef __attribute__((ext_vector_type(4))) float f32x4;

// fp32 -> bf16 bits, round-to-nearest-even (self-contained, no hip_bf16 dep)
__device__ __forceinline__ short f2bf_bits(float x){
  uint32_t u = __builtin_bit_cast(uint32_t, x);
  u += 0x7FFFu + ((u >> 16) & 1u);
  return (short)(u >> 16);
}

__device__ __forceinline__ short8 cvt8(f32x4 lo, f32x4 hi){
  short8 r;
  r[0]=f2bf_bits(lo[0]); r[1]=f2bf_bits(lo[1]); r[2]=f2bf_bits(lo[2]); r[3]=f2bf_bits(lo[3]);
  r[4]=f2bf_bits(hi[0]); r[5]=f2bf_bits(hi[1]); r[6]=f2bf_bits(hi[2]); r[7]=f2bf_bits(hi[3]);
  return r;
}

// Kernel 0: features [8192][32] fp32 -> Xt [32][8192] bf16
__global__ __launch_bounds__(256) void prep_xt(const float* __restrict__ X, short* __restrict__ Xt){
  int i = blockIdx.x * 256 + threadIdx.x;      // 0 .. 262143
  int r = i >> 5, c = i & 31;
  Xt[(size_t)c * NN + r] = f2bf_bits(X[i]);
}

// Kernel 1: Y1p/Y2p[ks][row][0..31] += adj{1,2}[rows][krange] @ X[krange][0..31]
// wave = 16 rows; block = 4 waves = 64 rows; grid (128, SPLITS)
__global__ __launch_bounds__(256) void gcn_mm1(const float* __restrict__ adj1, const float* __restrict__ adj2,
                                               const short* __restrict__ Xt,
                                               float* __restrict__ Y1p, float* __restrict__ Y2p, int klen){
  const int lane = threadIdx.x & 63;
  const int wave = threadIdx.x >> 6;
  const int bm   = blockIdx.x;
  const int ks   = blockIdx.y;
  const int arow = bm * 64 + wave * 16 + (lane & 15);
  const int kgrp = (lane >> 4) * 8;
  const int k0   = ks * klen;

  const float* a1  = adj1 + (size_t)arow * NN + k0 + kgrp;
  const float* a2  = adj2 + (size_t)arow * NN + k0 + kgrp;
  const short* bp0 = Xt + (size_t)(lane & 15) * NN + k0 + kgrp;
  const short* bp1 = bp0 + (size_t)16 * NN;

  f32x4 acc10 = {0.f,0.f,0.f,0.f}, acc11 = {0.f,0.f,0.f,0.f};
  f32x4 acc20 = {0.f,0.f,0.f,0.f}, acc21 = {0.f,0.f,0.f,0.f};

  const int nsteps = klen >> 5;
  #pragma unroll 4
  for (int t = 0; t < nsteps; ++t){
    f32x4 a1lo = *(const f32x4*)(a1);
    f32x4 a1hi = *(const f32x4*)(a1 + 4);
    f32x4 a2lo = *(const f32x4*)(a2);
    f32x4 a2hi = *(const f32x4*)(a2 + 4);
    short8 b0  = *(const short8*)(bp0);
    short8 b1  = *(const short8*)(bp1);
    short8 fa1 = cvt8(a1lo, a1hi);
    short8 fa2 = cvt8(a2lo, a2hi);
    acc10 = __builtin_amdgcn_mfma_f32_16x16x32_bf16(fa1, b0, acc10, 0, 0, 0);
    acc11 = __builtin_amdgcn_mfma_f32_16x16x32_bf16(fa1, b1, acc11, 0, 0, 0);
    acc20 = __builtin_amdgcn_mfma_f32_16x16x32_bf16(fa2, b0, acc20, 0, 0, 0);
    acc21 = __builtin_amdgcn_mfma_f32_16x16x32_bf16(fa2, b1, acc21, 0, 0, 0);
    a1 += 32; a2 += 32; bp0 += 32; bp1 += 32;
  }

  // D layout: col = lane&15, row = (lane>>4)*4 + reg   [verified m89/m91]
  const int orow = bm * 64 + wave * 16 + (lane >> 4) * 4;
  const int col  = lane & 15;
  float* y1 = Y1p + ((size_t)ks * NN + orow) * IN_DIM + col;
  float* y2 = Y2p + ((size_t)ks * NN + orow) * IN_DIM + col;
  #pragma unroll
  for (int r = 0; r < 4; ++r){
    y1[(size_t)r * IN_DIM]      = acc10[r];
    y1[(size_t)r * IN_DIM + 16] = acc11[r];
    y2[(size_t)r * IN_DIM]      = acc20[r];
    y2[(size_t)r * IN_DIM + 16] = acc21[r];
  }
}

// Kernel 2: h1t[c][row] = bf16( relu(Y1@W1+b1) + relu(Y2@W1+b1) ), 4 rows/block
__global__ __launch_bounds__(256) void l1_combine(const float* __restrict__ Y1p, const float* __restrict__ Y2p,
                                                  const float* __restrict__ W1, const float* __restrict__ b1,
                                                  short* __restrict__ H1t, int S){
  __shared__ float sW[IN_DIM * HID_DIM];
  __shared__ float sb[HID_DIM];
  __shared__ float sy[4][2][IN_DIM];
  const int tid = threadIdx.x;
  for (int i = tid; i < IN_DIM * HID_DIM; i += 256) sW[i] = W1[i];
  if (tid < HID_DIM) sb[tid] = b1[tid];
  const int sub = tid >> 6, t = tid & 63;
  const int row = blockIdx.x * 4 + sub;
  {
    const int br = t >> 5, c = t & 31;
    const float* P = br ? Y2p : Y1p;
    float s = 0.f;
    for (int sp = 0; sp < S; ++sp) s += P[((size_t)sp * NN + row) * IN_DIM + c];
    sy[sub][br][c] = s;
  }
  __syncthreads();
  float h1v = sb[t], h2v = sb[t];
  #pragma unroll
  for (int k = 0; k < IN_DIM; ++k){
    h1v += sy[sub][0][k] * sW[k * HID_DIM + t];
    h2v += sy[sub][1][k] * sW[k * HID_DIM + t];
  }
  float h = fmaxf(h1v, 0.f) + fmaxf(h2v, 0.f);
  H1t[(size_t)t * NN + row] = f2bf_bits(h);
}

// Kernel 3: Z1p/Z2p[ks][row][0..63] = adj{1,2}[rows][kr] @ h1[kr][0..63]
__global__ __launch_bounds__(256) void gcn_mm2(const float* __restrict__ adj1, const float* __restrict__ adj2,
                                               const short* __restrict__ H1t,
                                               float* __restrict__ Z1p, float* __restrict__ Z2p, int klen){
  const int lane = threadIdx.x & 63;
  const int wave = threadIdx.x >> 6;
  const int bm   = blockIdx.x;
  const int ks   = blockIdx.y;
  const int arow = bm * 64 + wave * 16 + (lane & 15);
  const int kgrp = (lane >> 4) * 8;
  const int k0   = ks * klen;

  const float* a1 = adj1 + (size_t)arow * NN + k0 + kgrp;
  const float* a2 = adj2 + (size_t)arow * NN + k0 + kgrp;
  const short* bp[4];
  #pragma unroll
  for (int f = 0; f < 4; ++f)
    bp[f] = H1t + (size_t)(f * 16 + (lane & 15)) * NN + k0 + kgrp;

  f32x4 acc1[4] = {{0.f,0.f,0.f,0.f},{0.f,0.f,0.f,0.f},{0.f,0.f,0.f,0.f},{0.f,0.f,0.f,0.f}};
  f32x4 acc2[4] = {{0.f,0.f,0.f,0.f},{0.f,0.f,0.f,0.f},{0.f,0.f,0.f,0.f},{0.f,0.f,0.f,0.f}};

  const int nsteps = klen >> 5;
  #pragma unroll 2
  for (int t = 0; t < nsteps; ++t){
    f32x4 a1lo = *(const f32x4*)(a1);
    f32x4 a1hi = *(const f32x4*)(a1 + 4);
    f32x4 a2lo = *(const f32x4*)(a2);
    f32x4 a2hi = *(const f32x4*)(a2 + 4);
    short8 b[4];
    #pragma unroll
    for (int f = 0; f < 4; ++f) b[f] = *(const short8*)(bp[f]);
    short8 fa1 = cvt8(a1lo, a1hi);
    short8 fa2 = cvt8(a2lo, a2hi);
    #pragma unroll
    for (int f = 0; f < 4; ++f){
      acc1[f] = __builtin_amdgcn_mfma_f32_16x16x32_bf16(fa1, b[f], acc1[f], 0, 0, 0);
      acc2[f] = __builtin_amdgcn_mfma_f32_16x16x32_bf16(fa2, b[f], acc2[f], 0, 0, 0);
    }
    a1 += 32; a2 += 32;
    #pragma unroll
    for (int f = 0; f < 4; ++f) bp[f] += 32;
  }

  const int orow = bm * 64 + wave * 16 + (lane >> 4) * 4;
  const int col  = lane & 15;
  float* z1 = Z1p + ((size_t)ks * NN + orow) * HID_DIM + col;
  float* z2 = Z2p + ((size_t)ks * NN + orow) * HID_DIM + col;
  #pragma unroll
  for (int r = 0; r < 4; ++r){
    #pragma unroll
    for (int f = 0; f < 4; ++f){
      z1[(size_t)r * HID_DIM + f * 16] = acc1[f][r];
      z2[(size_t)r * HID_DIM + f * 16] = acc2[f][r];
    }
  }
}

// Kernel 4: out[row][c] = relu(Z1@W2+b2) + relu(Z2@W2+b2), 4 rows/block
__global__ __launch_bounds__(256) void l2_combine(const float* __restrict__ Z1p, const float* __restrict__ Z2p,
                                                  const float* __restrict__ W2, const float* __restrict__ b2,
                                                  float* __restrict__ out, int S){
  __shared__ float sW[HID_DIM * OUT_DIM];
  __shared__ float sb[OUT_DIM];
  __shared__ float sz[4][2][HID_DIM];
  const int tid = threadIdx.x;
  for (int i = tid; i < HID_DIM * OUT_DIM; i += 256) sW[i] = W2[i];
  if (tid < OUT_DIM) sb[tid] = b2[tid];
  const int sub = tid >> 6, t = tid & 63;
  const int row = blockIdx.x * 4 + sub;
  float s1 = 0.f, s2 = 0.f;
  for (int sp = 0; sp < S; ++sp){
    s1 += Z1p[((size_t)sp * NN + row) * HID_DIM + t];
    s2 += Z2p[((size_t)sp * NN + row) * HID_DIM + t];
  }
  sz[sub][0][t] = s1;
  sz[sub][1][t] = s2;
  __syncthreads();
  if (t < OUT_DIM){
    float a = sb[t], b = sb[t];
    #pragma unroll
    for (int k = 0; k < HID_DIM; ++k){
      a += sz[sub][0][k] * sW[k * OUT_DIM + t];
      b += sz[sub][1][k] * sW[k * OUT_DIM + t];
    }
    out[(size_t)row * OUT_DIM + t] = fmaxf(a, 0.f) + fmaxf(b, 0.f);
  }
}

extern "C" void kernel_launch(void* const* d_in, const int* in_sizes, int n_in,
                              void* d_out, int out_size, void* d_ws, size_t ws_size,
                              hipStream_t stream){
  const float* adj1 = (const float*)d_in[0];
  const float* adj2 = (const float*)d_in[1];
  const float* X    = (const float*)d_in[2];
  const float* W1   = (const float*)d_in[3];
  const float* b1   = (const float*)d_in[4];
  const float* W2   = (const float*)d_in[5];
  const float* b2   = (const float*)d_in[6];
  float* out = (float*)d_out;

  char* ws = (char*)d_ws;
  short* Xt  = (short*)ws;                         // 32*8192*2  = 512 KB
  short* H1t = (short*)(ws + (size_t)512 * 1024);  // 64*8192*2  = 1 MB
  size_t off = (size_t)1536 * 1024;

  // pick K-split so partial buffers fit ws: per split 6 MB (Y: 2 MB, Z: 4 MB)
  int S = 4;
  while (S > 1 && off + (size_t)S * 6 * 1024 * 1024 > ws_size) S >>= 1;
  float* Y1p = (float*)(ws + off);
  float* Y2p = Y1p + (size_t)S * NN * IN_DIM;
  float* Z1p = Y2p + (size_t)S * NN * IN_DIM;
  float* Z2p = Z1p + (size_t)S * NN * HID_DIM;
  const int klen = NN / S;

  prep_xt  <<<dim3(NN * IN_DIM / 256), dim3(256), 0, stream>>>(X, Xt);
  gcn_mm1  <<<dim3(NN / 64, S), dim3(256), 0, stream>>>(adj1, adj2, Xt, Y1p, Y2p, klen);
  l1_combine<<<dim3(NN / 4), dim3(256), 0, stream>>>(Y1p, Y2p, W1, b1, H1t, S);
  gcn_mm2  <<<dim3(NN / 64, S), dim3(256), 0, stream>>>(adj1, adj2, H1t, Z1p, Z2p, klen);
  l2_combine<<<dim3(NN / 4), dim3(256), 0, stream>>>(Z1p, Z2p, W2, b2, out, S);
}